// Round 5
// baseline (507.134 us; speedup 1.0000x reference)
//
#include <hip/hip_runtime.h>
#include <cstdint>

#define Hq 16
#define HKVn 8
#define DHn 128
#define Tn 2048
#define Bn 2
#define Dm 2048
#define BT (Bn*Tn)   // 4096

typedef __attribute__((ext_vector_type(8))) short bfrag8;   // 8 bf16 (4 VGPRs)
typedef __attribute__((ext_vector_type(4))) float facc4;    // 4 fp32 acc
typedef __attribute__((ext_vector_type(4))) _Float16 f16x4; // 4 fp16 (2 VGPRs)
typedef __attribute__((ext_vector_type(8))) _Float16 f16x8; // 8 fp16 (4 VGPRs)
typedef __attribute__((ext_vector_type(8))) unsigned short us8;

__device__ __forceinline__ unsigned short f2bf(float f) {
    union { float f; unsigned int u; } v; v.f = f;
    unsigned int u = v.u;
    unsigned int r = (u + 0x7FFFu + ((u >> 16) & 1u)) >> 16;
    return (unsigned short)r;
}
__device__ __forceinline__ float bf2f(unsigned short u) {
    union { unsigned int u; float f; } v; v.u = ((unsigned int)u) << 16;
    return v.f;
}

// ---------------- fused fp32 -> bf16 convert + RoPE cos/sin LUT ----------------
// blocks 0..20479: convert; blocks 20480..20991: LUT (t in 0..2047, d in 0..63)
__global__ __launch_bounds__(256) void cvt_all(const float* __restrict__ x,
                                               const float* __restrict__ wq,
                                               const float* __restrict__ wk,
                                               const float* __restrict__ wv,
                                               const float* __restrict__ wo,
                                               unsigned short* __restrict__ x_bf,
                                               unsigned short* __restrict__ wqkv_bf,
                                               unsigned short* __restrict__ wo_bf,
                                               float* __restrict__ lut) {
    int i = blockIdx.x * 256 + threadIdx.x;   // float4 index, total 5242880
    if (i >= 5242880) {
        int ii = i - 5242880;                 // 0..131071
        int t = ii >> 6, d = ii & 63;
        float fr = exp2f(-(float)d * 0.3114307588956902f);
        float ang = (float)t * fr;
        float sv, cv;
        __sincosf(ang, &sv, &cv);
        lut[t * 128 + d] = cv;
        lut[t * 128 + 64 + d] = sv;
        return;
    }
    const float4* src; ushort4* dst;
    if (i < 2097152)      { src = (const float4*)x  + i;            dst = (ushort4*)x_bf + i; }
    else if (i < 3145728) { src = (const float4*)wq + (i-2097152);  dst = (ushort4*)wqkv_bf + (i-2097152); }
    else if (i < 3670016) { src = (const float4*)wk + (i-3145728);  dst = (ushort4*)wqkv_bf + 1048576 + (i-3145728); }
    else if (i < 4194304) { src = (const float4*)wv + (i-3670016);  dst = (ushort4*)wqkv_bf + 1572864 + (i-3670016); }
    else                  { src = (const float4*)wo + (i-4194304);  dst = (ushort4*)wo_bf + (i-4194304); }
    float4 v = *src;
    ushort4 y;
    y.x = f2bf(v.x); y.y = f2bf(v.y); y.z = f2bf(v.z); y.w = f2bf(v.w);
    *dst = y;
}

// K tiled-layout element offset within a (b,hkv) plane (attn-kernel K layout).
__device__ __forceinline__ size_t koff_tiled(int t, int d) {
    int kc = (t >> 4) & 3, l15 = t & 15;
    int f = d >> 5, qd = (d >> 3) & 3, j = d & 7;
    return (size_t)(t >> 6) * 8192 + ((((kc * 4 + f) * 64 + qd * 16 + l15) << 3) + j);
}

// ---------------- bf16 GEMM (out-proj): C[M][N] = A[M][K] @ B[N][K]^T, fp32 out ------
__global__ __launch_bounds__(256) void gemm_bt(const unsigned short* __restrict__ A,
                                               const unsigned short* __restrict__ Bm,
                                               float* __restrict__ C,
                                               int M, int N, int K) {
    __shared__ char smem[32768];   // As[128][64] @0, Bs[128][64] @16384
    int tid = threadIdx.x;
    int w = tid >> 6, lane = tid & 63, quad = lane >> 4, l15 = lane & 15;
    int wr = w >> 1, wc = w & 1;
    int rowBase = blockIdx.y * 128, colBase = blockIdx.x * 128;
    facc4 acc[4][4];
#pragma unroll
    for (int i = 0; i < 4; i++)
#pragma unroll
        for (int j = 0; j < 4; j++) acc[i][j] = facc4{0.f, 0.f, 0.f, 0.f};

    for (int k0 = 0; k0 < K; k0 += 64) {
        __syncthreads();
#pragma unroll
        for (int i4 = 0; i4 < 4; i4++) {
            int c = i4 * 256 + tid;
            int r = c >> 3, kkg = (c & 7) ^ (r & 7);
            const unsigned short* ga = A + (size_t)(rowBase + r) * K + k0 + kkg * 8;
            __builtin_amdgcn_global_load_lds((const __attribute__((address_space(1))) void*)ga,
                (__attribute__((address_space(3))) void*)(smem + i4 * 4096 + w * 1024), 16, 0, 0);
            const unsigned short* gb = Bm + (size_t)(colBase + r) * K + k0 + kkg * 8;
            __builtin_amdgcn_global_load_lds((const __attribute__((address_space(1))) void*)gb,
                (__attribute__((address_space(3))) void*)(smem + 16384 + i4 * 4096 + w * 1024), 16, 0, 0);
        }
        __syncthreads();
#pragma unroll
        for (int kh = 0; kh < 2; kh++) {
            bfrag8 af[4], bf[4];
#pragma unroll
            for (int i = 0; i < 4; i++) {
                int row = wr * 64 + i * 16 + l15;
                int ch = row * 8 + ((kh * 4 + quad) ^ (row & 7));
                af[i] = *(const bfrag8*)(smem + ch * 16);
            }
#pragma unroll
            for (int j = 0; j < 4; j++) {
                int row = wc * 64 + j * 16 + l15;
                int ch = row * 8 + ((kh * 4 + quad) ^ (row & 7));
                bf[j] = *(const bfrag8*)(smem + 16384 + ch * 16);
            }
#pragma unroll
            for (int i = 0; i < 4; i++)
#pragma unroll
                for (int j = 0; j < 4; j++)
                    acc[i][j] = __builtin_amdgcn_mfma_f32_16x16x32_bf16(af[i], bf[j], acc[i][j], 0, 0, 0);
        }
    }
#pragma unroll
    for (int i = 0; i < 4; i++)
#pragma unroll
        for (int j = 0; j < 4; j++)
#pragma unroll
            for (int r = 0; r < 4; r++) {
                int row = rowBase + wr * 64 + i * 16 + quad * 4 + r;
                int col = colBase + wc * 64 + j * 16 + l15;
                C[(size_t)row * N + col] = acc[i][j][r];
            }
}

// ---------------- fused QKV GEMM + RMSNorm + RoPE(LUT) + relayout --------------------
__global__ __launch_bounds__(256) void gemm_qkv_fused(const unsigned short* __restrict__ A,
                                                      const unsigned short* __restrict__ Bm,
                                                      const float* __restrict__ qw,
                                                      const float* __restrict__ kw,
                                                      const float* __restrict__ lut,
                                                      unsigned short* __restrict__ q_bf,
                                                      unsigned short* __restrict__ k_bf,
                                                      _Float16* __restrict__ vT) {
    __shared__ char smem[35840];
    const int K = 2048;
    int tid = threadIdx.x;
    int w = tid >> 6, lane = tid & 63, quad = lane >> 4, l15 = lane & 15;
    int wr = w >> 1, wc = w & 1;
    int bx = blockIdx.x;
    int rowBase = blockIdx.y * 128, colBase = bx * 128;
    facc4 acc[4][4];
#pragma unroll
    for (int i = 0; i < 4; i++)
#pragma unroll
        for (int j = 0; j < 4; j++) acc[i][j] = facc4{0.f, 0.f, 0.f, 0.f};

    for (int k0 = 0; k0 < K; k0 += 64) {
        __syncthreads();
#pragma unroll
        for (int i4 = 0; i4 < 4; i4++) {
            int c = i4 * 256 + tid;
            int r = c >> 3, kkg = (c & 7) ^ (r & 7);
            const unsigned short* ga = A + (size_t)(rowBase + r) * K + k0 + kkg * 8;
            __builtin_amdgcn_global_load_lds((const __attribute__((address_space(1))) void*)ga,
                (__attribute__((address_space(3))) void*)(smem + i4 * 4096 + w * 1024), 16, 0, 0);
            const unsigned short* gb = Bm + (size_t)(colBase + r) * K + k0 + kkg * 8;
            __builtin_amdgcn_global_load_lds((const __attribute__((address_space(1))) void*)gb,
                (__attribute__((address_space(3))) void*)(smem + 16384 + i4 * 4096 + w * 1024), 16, 0, 0);
        }
        __syncthreads();
#pragma unroll
        for (int kh = 0; kh < 2; kh++) {
            bfrag8 af[4], bf[4];
#pragma unroll
            for (int i = 0; i < 4; i++) {
                int row = wr * 64 + i * 16 + l15;
                int ch = row * 8 + ((kh * 4 + quad) ^ (row & 7));
                af[i] = *(const bfrag8*)(smem + ch * 16);
            }
#pragma unroll
            for (int j = 0; j < 4; j++) {
                int row = wc * 64 + j * 16 + l15;
                int ch = row * 8 + ((kh * 4 + quad) ^ (row & 7));
                bf[j] = *(const bfrag8*)(smem + 16384 + ch * 16);
            }
#pragma unroll
            for (int i = 0; i < 4; i++)
#pragma unroll
                for (int j = 0; j < 4; j++)
                    acc[i][j] = __builtin_amdgcn_mfma_f32_16x16x32_bf16(af[i], bf[j], acc[i][j], 0, 0, 0);
        }
    }

    if (bx >= 24) {
        // ---- V epilogue: fp32 acc -> fp16 tiled layout, direct from regs ----
        int hv = bx - 24;
        int gt0 = rowBase + wr * 64;
        int bb = gt0 >> 11;
        int t64 = (gt0 & 2047) >> 6;
        _Float16* base = vT + ((size_t)(bb * 8 + hv) * 32 + t64) * 8192;
#pragma unroll
        for (int i = 0; i < 4; i++) {
            int kcp = i >> 1, hh = i & 1;
#pragma unroll
            for (int j = 0; j < 4; j++) {
                int dblk = wc * 4 + j;
                f16x4 pv;
#pragma unroll
                for (int r = 0; r < 4; r++) pv[r] = (_Float16)acc[i][j][r];
                *(f16x4*)(base + (((dblk * 2 + kcp) * 64 + quad * 16 + l15) * 8) + hh * 4) = pv;
            }
        }
        return;
    }

    // ---- Q/K epilogue: RMSNorm + RoPE(LUT) + relayout ----
    const float* wn = (bx < 16) ? qw : kw;
    const float osc = (bx < 16) ? (0.08838834764831845f * 1.4426950408889634f) : 1.0f;
    float* sums = (float*)(smem + 34816);
    float ssum[4][4];
#pragma unroll
    for (int i = 0; i < 4; i++)
#pragma unroll
        for (int r = 0; r < 4; r++) {
            float s = 0.f;
#pragma unroll
            for (int j = 0; j < 4; j++) s += acc[i][j][r] * acc[i][j][r];
            s += __shfl_xor(s, 1); s += __shfl_xor(s, 2);
            s += __shfl_xor(s, 4); s += __shfl_xor(s, 8);
            ssum[i][r] = s;
        }
    if (l15 == 0) {
#pragma unroll
        for (int i = 0; i < 4; i++)
#pragma unroll
            for (int r = 0; r < 4; r++)
                sums[wc * 128 + wr * 64 + i * 16 + quad * 4 + r] = ssum[i][r];
    }
    __syncthreads();
    unsigned short* tile = (unsigned short*)smem;   // [128][136] bf16
    float wcol[4];
#pragma unroll
    for (int j = 0; j < 4; j++) wcol[j] = wn[wc * 64 + j * 16 + l15];
#pragma unroll
    for (int i = 0; i < 4; i++)
#pragma unroll
        for (int r = 0; r < 4; r++) {
            int row = wr * 64 + i * 16 + quad * 4 + r;
            float tot = sums[row] + sums[128 + row];
            float inv = rsqrtf(tot * (1.0f / 128.0f) + 1e-6f);
#pragma unroll
            for (int j = 0; j < 4; j++)
                tile[row * 136 + wc * 64 + j * 16 + l15] = f2bf(acc[i][j][r] * inv * wcol[j]);
        }
    __syncthreads();
    {
        int row = tid >> 1, d0 = (tid & 1) * 32;
        int gt = rowBase + row;
        int t = gt & 2047, bb = gt >> 11;
        unsigned short* qrow = q_bf + ((size_t)(bb * 16 + bx) * 2048 + t) * 128;
        unsigned short* kplane = k_bf + (size_t)(bb * 8 + (bx - 16)) * 2048 * 128;
        const float* lc = lut + t * 128;
#pragma unroll
        for (int dc = 0; dc < 32; dc += 8) {
            int db = d0 + dc;
            us8 n0u = *(const us8*)(tile + row * 136 + db);
            us8 n1u = *(const us8*)(tile + row * 136 + db + 64);
            float4 cA = *(const float4*)(lc + db), cB = *(const float4*)(lc + db + 4);
            float4 sA = *(const float4*)(lc + 64 + db), sB = *(const float4*)(lc + 64 + db + 4);
            float cv[8] = {cA.x, cA.y, cA.z, cA.w, cB.x, cB.y, cB.z, cB.w};
            float sv[8] = {sA.x, sA.y, sA.z, sA.w, sB.x, sB.y, sB.z, sB.w};
            us8 p0, p1;
#pragma unroll
            for (int e = 0; e < 8; e++) {
                float a0 = bf2f(n0u[e]), a1 = bf2f(n1u[e]);
                p0[e] = f2bf((a0 * cv[e] - a1 * sv[e]) * osc);
                p1[e] = f2bf((a1 * cv[e] + a0 * sv[e]) * osc);
            }
            if (bx < 16) {
                *(us8*)(qrow + db) = p0;
                *(us8*)(qrow + db + 64) = p1;
            } else {
                *(us8*)(kplane + koff_tiled(t, db)) = p0;
                *(us8*)(kplane + koff_tiled(t, db + 64)) = p1;
            }
        }
    }
}

// ---------------- flash attention v4: barrier-free, fragments direct from global ------
__global__ __launch_bounds__(256, 2) void attn_kernel(const unsigned short* __restrict__ q_bf,
                                                      const unsigned short* __restrict__ k_glob,
                                                      const _Float16* __restrict__ v_glob,
                                                      unsigned short* __restrict__ ctx) {
    int tid = threadIdx.x;
    int w = tid >> 6, lane = tid & 63, quad = lane >> 4, l15 = lane & 15;
    int bid = blockIdx.x;
    int u = bid & 255, halfg = bid >> 8;
    int j = u & 7, h = (u >> 3) & 15, b = (u >> 7) & 1;
    int qblk = halfg ? j : 15 - j;
    int hkv = h >> 1;
    int qb = qblk * 128;
    int qw0 = qb + w * 32;               // this wave's 32 q rows

    const unsigned short* qp = q_bf + (size_t)(b * Hq + h) * Tn * 128;
    const unsigned short* ktile = k_glob + (size_t)(b * HKVn + hkv) * 32 * 8192;
    const _Float16* vtile = v_glob + (size_t)(b * HKVn + hkv) * 32 * 8192;

    bfrag8 qf[2][4];
#pragma unroll
    for (int g = 0; g < 2; g++) {
        int row = qw0 + g * 16 + l15;
#pragma unroll
        for (int f = 0; f < 4; f++)
            qf[g][f] = *(const bfrag8*)(qp + (size_t)row * 128 + f * 32 + quad * 8);
    }

    facc4 o0[8], o1[8];
#pragma unroll
    for (int jj = 0; jj < 8; jj++) { o0[jj] = facc4{0.f,0.f,0.f,0.f}; o1[jj] = facc4{0.f,0.f,0.f,0.f}; }
    float m0 = -__builtin_inff(), m1 = -__builtin_inff(), l0 = 0.f, l1 = 0.f;

    int nkb = (qw0 >> 6) + 1;            // per-wave causal bound
    for (int ib = 0; ib < nkb; ib++) {
        int kb = ib * 64;
        const unsigned short* kt = ktile + (size_t)ib * 8192;
        const _Float16* vt = vtile + (size_t)ib * 8192;
        // S^T = K·Q^T : lane holds S^T[k = kb+kc*16+quad*4+r][q = qw0+(g)*16+l15]
        facc4 s0[4], s1[4];
#pragma unroll
        for (int kc = 0; kc < 4; kc++) {
            bfrag8 kf[4];
#pragma unroll
            for (int f = 0; f < 4; f++)
                kf[f] = *(const bfrag8*)(kt + ((kc * 4 + f) * 64 + lane) * 8);
            facc4 a = facc4{0.f,0.f,0.f,0.f}, bq = facc4{0.f,0.f,0.f,0.f};
#pragma unroll
            for (int f = 0; f < 4; f++) {
                a  = __builtin_amdgcn_mfma_f32_16x16x32_bf16(kf[f], qf[0][f], a, 0, 0, 0);
                bq = __builtin_amdgcn_mfma_f32_16x16x32_bf16(kf[f], qf[1][f], bq, 0, 0, 0);
            }
            s0[kc] = a; s1[kc] = bq;
        }
        if (kb + 63 > qw0) {             // diagonal: causal mask
            int q0 = qw0 + l15, q1 = q0 + 16;
#pragma unroll
            for (int kc = 0; kc < 4; kc++)
#pragma unroll
                for (int r = 0; r < 4; r++) {
                    int k = kb + kc * 16 + quad * 4 + r;
                    if (k > q0) s0[kc][r] = -__builtin_inff();
                    if (k > q1) s1[kc][r] = -__builtin_inff();
                }
        }
        float mx0 = s0[0][0], mx1 = s1[0][0];
#pragma unroll
        for (int kc = 0; kc < 4; kc++)
#pragma unroll
            for (int r = 0; r < 4; r++) {
                mx0 = fmaxf(mx0, s0[kc][r]); mx1 = fmaxf(mx1, s1[kc][r]);
            }
        mx0 = fmaxf(mx0, __shfl_xor(mx0, 16)); mx0 = fmaxf(mx0, __shfl_xor(mx0, 32));
        mx1 = fmaxf(mx1, __shfl_xor(mx1, 16)); mx1 = fmaxf(mx1, __shfl_xor(mx1, 32));
        float mn0 = fmaxf(m0, mx0), mn1 = fmaxf(m1, mx1);
        float alpha0 = exp2f(m0 - mn0), alpha1 = exp2f(m1 - mn1);
        m0 = mn0; m1 = mn1;
        float rs0 = 0.f, rs1 = 0.f;
#pragma unroll
        for (int kc = 0; kc < 4; kc++)
#pragma unroll
            for (int r = 0; r < 4; r++) {
                s0[kc][r] = exp2f(s0[kc][r] - m0); rs0 += s0[kc][r];
                s1[kc][r] = exp2f(s1[kc][r] - m1); rs1 += s1[kc][r];
            }
        rs0 += __shfl_xor(rs0, 16); rs0 += __shfl_xor(rs0, 32);
        rs1 += __shfl_xor(rs1, 16); rs1 += __shfl_xor(rs1, 32);
        l0 = l0 * alpha0 + rs0; l1 = l1 * alpha1 + rs1;
#pragma unroll
        for (int jj = 0; jj < 8; jj++)
#pragma unroll
            for (int r = 0; r < 4; r++) { o0[jj][r] *= alpha0; o1[jj][r] *= alpha1; }
        f16x4 pb0[4], pb1[4];
#pragma unroll
        for (int kc = 0; kc < 4; kc++) {
            pb0[kc] = f16x4{(_Float16)s0[kc][0], (_Float16)s0[kc][1],
                            (_Float16)s0[kc][2], (_Float16)s0[kc][3]};
            pb1[kc] = f16x4{(_Float16)s1[kc][0], (_Float16)s1[kc][1],
                            (_Float16)s1[kc][2], (_Float16)s1[kc][3]};
        }
        // PV: O^T[d][q] += V^T[d][k]·P^T[k][q], V frags direct from global
#pragma unroll
        for (int kcp = 0; kcp < 2; kcp++)
#pragma unroll
            for (int dblk = 0; dblk < 8; dblk++) {
                f16x8 vv = *(const f16x8*)(vt + ((dblk * 2 + kcp) * 64 + lane) * 8);
                f16x4 a0 = f16x4{vv[0], vv[1], vv[2], vv[3]};
                f16x4 a1 = f16x4{vv[4], vv[5], vv[6], vv[7]};
                o0[dblk] = __builtin_amdgcn_mfma_f32_16x16x16f16(a0, pb0[kcp*2],   o0[dblk], 0, 0, 0);
                o0[dblk] = __builtin_amdgcn_mfma_f32_16x16x16f16(a1, pb0[kcp*2+1], o0[dblk], 0, 0, 0);
                o1[dblk] = __builtin_amdgcn_mfma_f32_16x16x16f16(a0, pb1[kcp*2],   o1[dblk], 0, 0, 0);
                o1[dblk] = __builtin_amdgcn_mfma_f32_16x16x16f16(a1, pb1[kcp*2+1], o1[dblk], 0, 0, 0);
            }
    }
    float inv0 = 1.0f / l0, inv1 = 1.0f / l1;
#pragma unroll
    for (int g = 0; g < 2; g++) {
        int q = qw0 + g * 16 + l15;
        float invl = g ? inv1 : inv0;
#pragma unroll
        for (int dblk = 0; dblk < 8; dblk++) {
            facc4 ov = g ? o1[dblk] : o0[dblk];
            ushort4 st;
            st.x = f2bf(ov[0] * invl); st.y = f2bf(ov[1] * invl);
            st.z = f2bf(ov[2] * invl); st.w = f2bf(ov[3] * invl);
            *(ushort4*)(ctx + ((size_t)(b * Tn + q)) * 2048 + h * 128 + dblk * 16 + quad * 4) = st;
        }
    }
}

extern "C" void kernel_launch(void* const* d_in, const int* in_sizes, int n_in,
                              void* d_out, int out_size, void* d_ws, size_t ws_size,
                              hipStream_t stream) {
    (void)in_sizes; (void)n_in; (void)out_size; (void)ws_size;
    const float* x  = (const float*)d_in[0];
    const float* wq = (const float*)d_in[1];
    const float* wk = (const float*)d_in[2];
    const float* wv = (const float*)d_in[3];
    const float* wo = (const float*)d_in[4];
    const float* qw = (const float*)d_in[5];
    const float* kw = (const float*)d_in[6];
    float* out = (float*)d_out;
    char* ws = (char*)d_ws;

    unsigned short* x_bf    = (unsigned short*)(ws);               // 16.78 MB
    unsigned short* wqkv_bf = (unsigned short*)(ws + 16777216);    // 16.78 MB
    unsigned short* wo_bf   = (unsigned short*)(ws + 33554432);    //  8.39 MB
    unsigned short* q_bf    = (unsigned short*)(ws + 41943040);    // 16.78 MB [B][H][T][128]
    unsigned short* k_bf    = (unsigned short*)(ws + 58720256);    //  8.39 MB tiled
    _Float16*       vT_f16  = (_Float16*)(ws + 67108864);          //  8.39 MB tiled fp16
    unsigned short* ctx_bf  = (unsigned short*)(ws + 75497472);    // 16.78 MB [4096][2048]
    float*          lut     = (float*)(ws + 92274688);             //  1.05 MB [2048][128]

    cvt_all<<<20992, 256, 0, stream>>>(x, wq, wk, wv, wo, x_bf, wqkv_bf, wo_bf, lut);
    gemm_qkv_fused<<<dim3(32, 32), 256, 0, stream>>>(x_bf, wqkv_bf, qw, kw, lut, q_bf, k_bf, vT_f16);
    attn_kernel<<<512, 256, 0, stream>>>(q_bf, k_bf, vT_f16, ctx_bf);
    gemm_bt<<<dim3(16, 32), 256, 0, stream>>>(ctx_bf, wo_bf, out, 4096, 2048, 2048);
}

// Round 6
// 328.471 us; speedup vs baseline: 1.5439x; 1.5439x over previous
//
#include <hip/hip_runtime.h>
#include <cstdint>

#define Hq 16
#define HKVn 8
#define DHn 128
#define Tn 2048
#define Bn 2
#define Dm 2048
#define BT (Bn*Tn)   // 4096

typedef __attribute__((ext_vector_type(8))) short bfrag8;   // 8 bf16 (4 VGPRs)
typedef __attribute__((ext_vector_type(4))) float facc4;    // 4 fp32 acc
typedef __attribute__((ext_vector_type(4))) _Float16 f16x4; // 4 fp16 (2 VGPRs)
typedef __attribute__((ext_vector_type(8))) _Float16 f16x8; // 8 fp16 (4 VGPRs)
typedef __attribute__((ext_vector_type(8))) unsigned short us8;

__device__ __forceinline__ unsigned short f2bf(float f) {
    union { float f; unsigned int u; } v; v.f = f;
    unsigned int u = v.u;
    unsigned int r = (u + 0x7FFFu + ((u >> 16) & 1u)) >> 16;
    return (unsigned short)r;
}
__device__ __forceinline__ float bf2f(unsigned short u) {
    union { unsigned int u; float f; } v; v.u = ((unsigned int)u) << 16;
    return v.f;
}

// ---------------- fused fp32 -> bf16 convert + RoPE cos/sin LUT ----------------
__global__ __launch_bounds__(256) void cvt_all(const float* __restrict__ x,
                                               const float* __restrict__ wq,
                                               const float* __restrict__ wk,
                                               const float* __restrict__ wv,
                                               const float* __restrict__ wo,
                                               unsigned short* __restrict__ x_bf,
                                               unsigned short* __restrict__ wqkv_bf,
                                               unsigned short* __restrict__ wo_bf,
                                               float* __restrict__ lut) {
    int i = blockIdx.x * 256 + threadIdx.x;   // float4 index, total 5242880
    if (i >= 5242880) {
        int ii = i - 5242880;                 // 0..131071
        int t = ii >> 6, d = ii & 63;
        float fr = exp2f(-(float)d * 0.3114307588956902f);
        float ang = (float)t * fr;
        float sv, cv;
        __sincosf(ang, &sv, &cv);
        lut[t * 128 + d] = cv;
        lut[t * 128 + 64 + d] = sv;
        return;
    }
    const float4* src; ushort4* dst;
    if (i < 2097152)      { src = (const float4*)x  + i;            dst = (ushort4*)x_bf + i; }
    else if (i < 3145728) { src = (const float4*)wq + (i-2097152);  dst = (ushort4*)wqkv_bf + (i-2097152); }
    else if (i < 3670016) { src = (const float4*)wk + (i-3145728);  dst = (ushort4*)wqkv_bf + 1048576 + (i-3145728); }
    else if (i < 4194304) { src = (const float4*)wv + (i-3670016);  dst = (ushort4*)wqkv_bf + 1572864 + (i-3670016); }
    else                  { src = (const float4*)wo + (i-4194304);  dst = (ushort4*)wo_bf + (i-4194304); }
    float4 v = *src;
    ushort4 y;
    y.x = f2bf(v.x); y.y = f2bf(v.y); y.z = f2bf(v.z); y.w = f2bf(v.w);
    *dst = y;
}

// K tiled-layout element offset within a (b,hkv) plane (attn-kernel K layout).
__device__ __forceinline__ size_t koff_tiled(int t, int d) {
    int kc = (t >> 4) & 3, l15 = t & 15;
    int f = d >> 5, qd = (d >> 3) & 3, j = d & 7;
    return (size_t)(t >> 6) * 8192 + ((((kc * 4 + f) * 64 + qd * 16 + l15) << 3) + j);
}

// ---------------- bf16 GEMM (out-proj): C[M][N] = A[M][K] @ B[N][K]^T, fp32 out ------
__global__ __launch_bounds__(256) void gemm_bt(const unsigned short* __restrict__ A,
                                               const unsigned short* __restrict__ Bm,
                                               float* __restrict__ C,
                                               int M, int N, int K) {
    __shared__ char smem[32768];   // As[128][64] @0, Bs[128][64] @16384
    int tid = threadIdx.x;
    int w = tid >> 6, lane = tid & 63, quad = lane >> 4, l15 = lane & 15;
    int wr = w >> 1, wc = w & 1;
    int rowBase = blockIdx.y * 128, colBase = blockIdx.x * 128;
    facc4 acc[4][4];
#pragma unroll
    for (int i = 0; i < 4; i++)
#pragma unroll
        for (int j = 0; j < 4; j++) acc[i][j] = facc4{0.f, 0.f, 0.f, 0.f};

    for (int k0 = 0; k0 < K; k0 += 64) {
        __syncthreads();
#pragma unroll
        for (int i4 = 0; i4 < 4; i4++) {
            int c = i4 * 256 + tid;
            int r = c >> 3, kkg = (c & 7) ^ (r & 7);
            const unsigned short* ga = A + (size_t)(rowBase + r) * K + k0 + kkg * 8;
            __builtin_amdgcn_global_load_lds((const __attribute__((address_space(1))) void*)ga,
                (__attribute__((address_space(3))) void*)(smem + i4 * 4096 + w * 1024), 16, 0, 0);
            const unsigned short* gb = Bm + (size_t)(colBase + r) * K + k0 + kkg * 8;
            __builtin_amdgcn_global_load_lds((const __attribute__((address_space(1))) void*)gb,
                (__attribute__((address_space(3))) void*)(smem + 16384 + i4 * 4096 + w * 1024), 16, 0, 0);
        }
        __syncthreads();
#pragma unroll
        for (int kh = 0; kh < 2; kh++) {
            bfrag8 af[4], bf[4];
#pragma unroll
            for (int i = 0; i < 4; i++) {
                int row = wr * 64 + i * 16 + l15;
                int ch = row * 8 + ((kh * 4 + quad) ^ (row & 7));
                af[i] = *(const bfrag8*)(smem + ch * 16);
            }
#pragma unroll
            for (int j = 0; j < 4; j++) {
                int row = wc * 64 + j * 16 + l15;
                int ch = row * 8 + ((kh * 4 + quad) ^ (row & 7));
                bf[j] = *(const bfrag8*)(smem + 16384 + ch * 16);
            }
#pragma unroll
            for (int i = 0; i < 4; i++)
#pragma unroll
                for (int j = 0; j < 4; j++)
                    acc[i][j] = __builtin_amdgcn_mfma_f32_16x16x32_bf16(af[i], bf[j], acc[i][j], 0, 0, 0);
        }
    }
#pragma unroll
    for (int i = 0; i < 4; i++)
#pragma unroll
        for (int j = 0; j < 4; j++)
#pragma unroll
            for (int r = 0; r < 4; r++) {
                int row = rowBase + wr * 64 + i * 16 + quad * 4 + r;
                int col = colBase + wc * 64 + j * 16 + l15;
                C[(size_t)row * N + col] = acc[i][j][r];
            }
}

// ---------------- fused QKV GEMM + RMSNorm + RoPE(LUT) + relayout --------------------
__global__ __launch_bounds__(256) void gemm_qkv_fused(const unsigned short* __restrict__ A,
                                                      const unsigned short* __restrict__ Bm,
                                                      const float* __restrict__ qw,
                                                      const float* __restrict__ kw,
                                                      const float* __restrict__ lut,
                                                      unsigned short* __restrict__ q_bf,
                                                      unsigned short* __restrict__ k_bf,
                                                      _Float16* __restrict__ vT) {
    __shared__ char smem[35840];
    const int K = 2048;
    int tid = threadIdx.x;
    int w = tid >> 6, lane = tid & 63, quad = lane >> 4, l15 = lane & 15;
    int wr = w >> 1, wc = w & 1;
    int bx = blockIdx.x;
    int rowBase = blockIdx.y * 128, colBase = bx * 128;
    facc4 acc[4][4];
#pragma unroll
    for (int i = 0; i < 4; i++)
#pragma unroll
        for (int j = 0; j < 4; j++) acc[i][j] = facc4{0.f, 0.f, 0.f, 0.f};

    for (int k0 = 0; k0 < K; k0 += 64) {
        __syncthreads();
#pragma unroll
        for (int i4 = 0; i4 < 4; i4++) {
            int c = i4 * 256 + tid;
            int r = c >> 3, kkg = (c & 7) ^ (r & 7);
            const unsigned short* ga = A + (size_t)(rowBase + r) * K + k0 + kkg * 8;
            __builtin_amdgcn_global_load_lds((const __attribute__((address_space(1))) void*)ga,
                (__attribute__((address_space(3))) void*)(smem + i4 * 4096 + w * 1024), 16, 0, 0);
            const unsigned short* gb = Bm + (size_t)(colBase + r) * K + k0 + kkg * 8;
            __builtin_amdgcn_global_load_lds((const __attribute__((address_space(1))) void*)gb,
                (__attribute__((address_space(3))) void*)(smem + 16384 + i4 * 4096 + w * 1024), 16, 0, 0);
        }
        __syncthreads();
#pragma unroll
        for (int kh = 0; kh < 2; kh++) {
            bfrag8 af[4], bf[4];
#pragma unroll
            for (int i = 0; i < 4; i++) {
                int row = wr * 64 + i * 16 + l15;
                int ch = row * 8 + ((kh * 4 + quad) ^ (row & 7));
                af[i] = *(const bfrag8*)(smem + ch * 16);
            }
#pragma unroll
            for (int j = 0; j < 4; j++) {
                int row = wc * 64 + j * 16 + l15;
                int ch = row * 8 + ((kh * 4 + quad) ^ (row & 7));
                bf[j] = *(const bfrag8*)(smem + 16384 + ch * 16);
            }
#pragma unroll
            for (int i = 0; i < 4; i++)
#pragma unroll
                for (int j = 0; j < 4; j++)
                    acc[i][j] = __builtin_amdgcn_mfma_f32_16x16x32_bf16(af[i], bf[j], acc[i][j], 0, 0, 0);
        }
    }

    if (bx >= 24) {
        // ---- V epilogue: fp32 acc -> fp16 tiled layout, direct from regs ----
        int hv = bx - 24;
        int gt0 = rowBase + wr * 64;
        int bb = gt0 >> 11;
        int t64 = (gt0 & 2047) >> 6;
        _Float16* base = vT + ((size_t)(bb * 8 + hv) * 32 + t64) * 8192;
#pragma unroll
        for (int i = 0; i < 4; i++) {
            int kcp = i >> 1, hh = i & 1;
#pragma unroll
            for (int j = 0; j < 4; j++) {
                int dblk = wc * 4 + j;
                f16x4 pv;
#pragma unroll
                for (int r = 0; r < 4; r++) pv[r] = (_Float16)acc[i][j][r];
                *(f16x4*)(base + (((dblk * 2 + kcp) * 64 + quad * 16 + l15) * 8) + hh * 4) = pv;
            }
        }
        return;
    }

    // ---- Q/K epilogue: RMSNorm + RoPE(LUT) + relayout ----
    const float* wn = (bx < 16) ? qw : kw;
    const float osc = (bx < 16) ? (0.08838834764831845f * 1.4426950408889634f) : 1.0f;
    float* sums = (float*)(smem + 34816);
    float ssum[4][4];
#pragma unroll
    for (int i = 0; i < 4; i++)
#pragma unroll
        for (int r = 0; r < 4; r++) {
            float s = 0.f;
#pragma unroll
            for (int j = 0; j < 4; j++) s += acc[i][j][r] * acc[i][j][r];
            s += __shfl_xor(s, 1); s += __shfl_xor(s, 2);
            s += __shfl_xor(s, 4); s += __shfl_xor(s, 8);
            ssum[i][r] = s;
        }
    if (l15 == 0) {
#pragma unroll
        for (int i = 0; i < 4; i++)
#pragma unroll
            for (int r = 0; r < 4; r++)
                sums[wc * 128 + wr * 64 + i * 16 + quad * 4 + r] = ssum[i][r];
    }
    __syncthreads();
    unsigned short* tile = (unsigned short*)smem;   // [128][136] bf16
    float wcol[4];
#pragma unroll
    for (int j = 0; j < 4; j++) wcol[j] = wn[wc * 64 + j * 16 + l15];
#pragma unroll
    for (int i = 0; i < 4; i++)
#pragma unroll
        for (int r = 0; r < 4; r++) {
            int row = wr * 64 + i * 16 + quad * 4 + r;
            float tot = sums[row] + sums[128 + row];
            float inv = rsqrtf(tot * (1.0f / 128.0f) + 1e-6f);
#pragma unroll
            for (int j = 0; j < 4; j++)
                tile[row * 136 + wc * 64 + j * 16 + l15] = f2bf(acc[i][j][r] * inv * wcol[j]);
        }
    __syncthreads();
    {
        int row = tid >> 1, d0 = (tid & 1) * 32;
        int gt = rowBase + row;
        int t = gt & 2047, bb = gt >> 11;
        unsigned short* qrow = q_bf + ((size_t)(bb * 16 + bx) * 2048 + t) * 128;
        unsigned short* kplane = k_bf + (size_t)(bb * 8 + (bx - 16)) * 2048 * 128;
        const float* lc = lut + t * 128;
#pragma unroll
        for (int dc = 0; dc < 32; dc += 8) {
            int db = d0 + dc;
            us8 n0u = *(const us8*)(tile + row * 136 + db);
            us8 n1u = *(const us8*)(tile + row * 136 + db + 64);
            float4 cA = *(const float4*)(lc + db), cB = *(const float4*)(lc + db + 4);
            float4 sA = *(const float4*)(lc + 64 + db), sB = *(const float4*)(lc + 64 + db + 4);
            float cv[8] = {cA.x, cA.y, cA.z, cA.w, cB.x, cB.y, cB.z, cB.w};
            float sv[8] = {sA.x, sA.y, sA.z, sA.w, sB.x, sB.y, sB.z, sB.w};
            us8 p0, p1;
#pragma unroll
            for (int e = 0; e < 8; e++) {
                float a0 = bf2f(n0u[e]), a1 = bf2f(n1u[e]);
                p0[e] = f2bf((a0 * cv[e] - a1 * sv[e]) * osc);
                p1[e] = f2bf((a1 * cv[e] + a0 * sv[e]) * osc);
            }
            if (bx < 16) {
                *(us8*)(qrow + db) = p0;
                *(us8*)(qrow + db + 64) = p1;
            } else {
                *(us8*)(kplane + koff_tiled(t, db)) = p0;
                *(us8*)(kplane + koff_tiled(t, db + 64)) = p1;
            }
        }
    }
}

// ---------------- flash attention: S^T trick + dbuf prefetch + balanced sched ---------
// (reverted to the R4 structure: LDS dbuf, one barrier/iter, drain is one compute-phase old)
__global__ __launch_bounds__(256, 2) void attn_kernel(const unsigned short* __restrict__ q_bf,
                                                      const unsigned short* __restrict__ k_glob,
                                                      const _Float16* __restrict__ v_glob,
                                                      unsigned short* __restrict__ ctx) {
    __shared__ char smem[65536];   // dbuf: K 16KB + V 16KB per buffer
    int tid = threadIdx.x;
    int w = tid >> 6, lane = tid & 63, quad = lane >> 4, l15 = lane & 15;
    int bid = blockIdx.x;
    int u = bid & 255, halfg = bid >> 8;
    int j = u & 7, h = (u >> 3) & 15, b = (u >> 7) & 1;
    int qblk = halfg ? j : 15 - j;
    int hkv = h >> 1;
    int qb = qblk * 128;
    int qw0 = qb + w * 32;

    const unsigned short* qp = q_bf + (size_t)(b * Hq + h) * Tn * 128;
    const unsigned short* ktile = k_glob + (size_t)(b * HKVn + hkv) * 32 * 8192;
    const _Float16* vtile = v_glob + (size_t)(b * HKVn + hkv) * 32 * 8192;

    bfrag8 qf[2][4];
#pragma unroll
    for (int g = 0; g < 2; g++) {
        int row = qw0 + g * 16 + l15;
#pragma unroll
        for (int f = 0; f < 4; f++)
            qf[g][f] = *(const bfrag8*)(qp + (size_t)row * 128 + f * 32 + quad * 8);
    }

    facc4 o0[8], o1[8];
#pragma unroll
    for (int jj = 0; jj < 8; jj++) { o0[jj] = facc4{0.f,0.f,0.f,0.f}; o1[jj] = facc4{0.f,0.f,0.f,0.f}; }
    float m0 = -__builtin_inff(), m1 = -__builtin_inff(), l0 = 0.f, l1 = 0.f;

    int nkb = qb / 64 + 2;
#pragma unroll
    for (int i = 0; i < 4; i++) {
        const unsigned short* gk = ktile + (size_t)(i * 256 + tid) * 8;
        __builtin_amdgcn_global_load_lds((const __attribute__((address_space(1))) void*)gk,
            (__attribute__((address_space(3))) void*)(smem + i * 4096 + w * 1024), 16, 0, 0);
        const _Float16* gv = vtile + (size_t)(i * 256 + tid) * 8;
        __builtin_amdgcn_global_load_lds((const __attribute__((address_space(1))) void*)gv,
            (__attribute__((address_space(3))) void*)(smem + 16384 + i * 4096 + w * 1024), 16, 0, 0);
    }

    for (int ib = 0; ib < nkb; ib++) {
        int kb = ib * 64;
        __syncthreads();
        if (ib + 1 < nkb) {
            char* nb = smem + ((ib + 1) & 1) * 32768;
#pragma unroll
            for (int i = 0; i < 4; i++) {
                const unsigned short* gk = ktile + (size_t)(ib + 1) * 8192 + (i * 256 + tid) * 8;
                __builtin_amdgcn_global_load_lds((const __attribute__((address_space(1))) void*)gk,
                    (__attribute__((address_space(3))) void*)(nb + i * 4096 + w * 1024), 16, 0, 0);
                const _Float16* gv = vtile + (size_t)(ib + 1) * 8192 + (i * 256 + tid) * 8;
                __builtin_amdgcn_global_load_lds((const __attribute__((address_space(1))) void*)gv,
                    (__attribute__((address_space(3))) void*)(nb + 16384 + i * 4096 + w * 1024), 16, 0, 0);
            }
        }
        char* cb = smem + (ib & 1) * 32768;
        if (kb <= qw0 + 31) {
            facc4 s0[4], s1[4];
#pragma unroll
            for (int kc = 0; kc < 4; kc++) {
                bfrag8 kf[4];
#pragma unroll
                for (int f = 0; f < 4; f++)
                    kf[f] = *(const bfrag8*)(cb + (((kc * 4 + f) * 64 + lane) << 4));
                facc4 a = facc4{0.f,0.f,0.f,0.f}, bq = facc4{0.f,0.f,0.f,0.f};
#pragma unroll
                for (int f = 0; f < 4; f++) {
                    a  = __builtin_amdgcn_mfma_f32_16x16x32_bf16(kf[f], qf[0][f], a, 0, 0, 0);
                    bq = __builtin_amdgcn_mfma_f32_16x16x32_bf16(kf[f], qf[1][f], bq, 0, 0, 0);
                }
                s0[kc] = a; s1[kc] = bq;
            }
            if (kb + 63 > qw0) {
                int q0 = qw0 + l15, q1 = q0 + 16;
#pragma unroll
                for (int kc = 0; kc < 4; kc++)
#pragma unroll
                    for (int r = 0; r < 4; r++) {
                        int k = kb + kc * 16 + quad * 4 + r;
                        if (k > q0) s0[kc][r] = -__builtin_inff();
                        if (k > q1) s1[kc][r] = -__builtin_inff();
                    }
            }
            float mx0 = s0[0][0], mx1 = s1[0][0];
#pragma unroll
            for (int kc = 0; kc < 4; kc++)
#pragma unroll
                for (int r = 0; r < 4; r++) {
                    mx0 = fmaxf(mx0, s0[kc][r]); mx1 = fmaxf(mx1, s1[kc][r]);
                }
            mx0 = fmaxf(mx0, __shfl_xor(mx0, 16)); mx0 = fmaxf(mx0, __shfl_xor(mx0, 32));
            mx1 = fmaxf(mx1, __shfl_xor(mx1, 16)); mx1 = fmaxf(mx1, __shfl_xor(mx1, 32));
            float mn0 = fmaxf(m0, mx0), mn1 = fmaxf(m1, mx1);
            float alpha0 = exp2f(m0 - mn0), alpha1 = exp2f(m1 - mn1);
            m0 = mn0; m1 = mn1;
            float rs0 = 0.f, rs1 = 0.f;
#pragma unroll
            for (int kc = 0; kc < 4; kc++)
#pragma unroll
                for (int r = 0; r < 4; r++) {
                    s0[kc][r] = exp2f(s0[kc][r] - m0); rs0 += s0[kc][r];
                    s1[kc][r] = exp2f(s1[kc][r] - m1); rs1 += s1[kc][r];
                }
            rs0 += __shfl_xor(rs0, 16); rs0 += __shfl_xor(rs0, 32);
            rs1 += __shfl_xor(rs1, 16); rs1 += __shfl_xor(rs1, 32);
            l0 = l0 * alpha0 + rs0; l1 = l1 * alpha1 + rs1;
#pragma unroll
            for (int jj = 0; jj < 8; jj++)
#pragma unroll
                for (int r = 0; r < 4; r++) { o0[jj][r] *= alpha0; o1[jj][r] *= alpha1; }
            f16x4 pb0[4], pb1[4];
#pragma unroll
            for (int kc = 0; kc < 4; kc++) {
                pb0[kc] = f16x4{(_Float16)s0[kc][0], (_Float16)s0[kc][1],
                                (_Float16)s0[kc][2], (_Float16)s0[kc][3]};
                pb1[kc] = f16x4{(_Float16)s1[kc][0], (_Float16)s1[kc][1],
                                (_Float16)s1[kc][2], (_Float16)s1[kc][3]};
            }
#pragma unroll
            for (int kcp = 0; kcp < 2; kcp++)
#pragma unroll
                for (int dblk = 0; dblk < 8; dblk++) {
                    f16x8 vv = *(const f16x8*)(cb + 16384 + (((dblk * 2 + kcp) * 64 + lane) << 4));
                    f16x4 a0 = f16x4{vv[0], vv[1], vv[2], vv[3]};
                    f16x4 a1 = f16x4{vv[4], vv[5], vv[6], vv[7]};
                    o0[dblk] = __builtin_amdgcn_mfma_f32_16x16x16f16(a0, pb0[kcp*2],   o0[dblk], 0, 0, 0);
                    o0[dblk] = __builtin_amdgcn_mfma_f32_16x16x16f16(a1, pb0[kcp*2+1], o0[dblk], 0, 0, 0);
                    o1[dblk] = __builtin_amdgcn_mfma_f32_16x16x16f16(a0, pb1[kcp*2],   o1[dblk], 0, 0, 0);
                    o1[dblk] = __builtin_amdgcn_mfma_f32_16x16x16f16(a1, pb1[kcp*2+1], o1[dblk], 0, 0, 0);
                }
        }
    }
    float inv0 = 1.0f / l0, inv1 = 1.0f / l1;
#pragma unroll
    for (int g = 0; g < 2; g++) {
        int q = qw0 + g * 16 + l15;
        float invl = g ? inv1 : inv0;
#pragma unroll
        for (int dblk = 0; dblk < 8; dblk++) {
            facc4 ov = g ? o1[dblk] : o0[dblk];
            ushort4 st;
            st.x = f2bf(ov[0] * invl); st.y = f2bf(ov[1] * invl);
            st.z = f2bf(ov[2] * invl); st.w = f2bf(ov[3] * invl);
            *(ushort4*)(ctx + ((size_t)(b * Tn + q)) * 2048 + h * 128 + dblk * 16 + quad * 4) = st;
        }
    }
}

extern "C" void kernel_launch(void* const* d_in, const int* in_sizes, int n_in,
                              void* d_out, int out_size, void* d_ws, size_t ws_size,
                              hipStream_t stream) {
    (void)in_sizes; (void)n_in; (void)out_size; (void)ws_size;
    const float* x  = (const float*)d_in[0];
    const float* wq = (const float*)d_in[1];
    const float* wk = (const float*)d_in[2];
    const float* wv = (const float*)d_in[3];
    const float* wo = (const float*)d_in[4];
    const float* qw = (const float*)d_in[5];
    const float* kw = (const float*)d_in[6];
    float* out = (float*)d_out;
    char* ws = (char*)d_ws;

    unsigned short* x_bf    = (unsigned short*)(ws);               // 16.78 MB
    unsigned short* wqkv_bf = (unsigned short*)(ws + 16777216);    // 16.78 MB
    unsigned short* wo_bf   = (unsigned short*)(ws + 33554432);    //  8.39 MB
    unsigned short* q_bf    = (unsigned short*)(ws + 41943040);    // 16.78 MB [B][H][T][128]
    unsigned short* k_bf    = (unsigned short*)(ws + 58720256);    //  8.39 MB tiled
    _Float16*       vT_f16  = (_Float16*)(ws + 67108864);          //  8.39 MB tiled fp16
    unsigned short* ctx_bf  = (unsigned short*)(ws + 75497472);    // 16.78 MB [4096][2048]
    float*          lut     = (float*)(ws + 92274688);             //  1.05 MB [2048][128]

    cvt_all<<<20992, 256, 0, stream>>>(x, wq, wk, wv, wo, x_bf, wqkv_bf, wo_bf, lut);
    gemm_qkv_fused<<<dim3(32, 32), 256, 0, stream>>>(x_bf, wqkv_bf, qw, kw, lut, q_bf, k_bf, vT_f16);
    attn_kernel<<<512, 256, 0, stream>>>(q_bf, k_bf, vT_f16, ctx_bf);
    gemm_bt<<<dim3(16, 32), 256, 0, stream>>>(ctx_bf, wo_bf, out, 4096, 2048, 2048);
}